// Round 11
// baseline (652.542 us; speedup 1.0000x reference)
//
#include <hip/hip_runtime.h>
#include <hip/hip_fp16.h>

typedef _Float16 half8 __attribute__((ext_vector_type(8)));
typedef float f32x4 __attribute__((ext_vector_type(4)));

#define GRID_BLKS 1024     // 4 blocks/CU x 256 CUs -- must stay co-resident
#define GT 16              // rows per g-phase tile
#define ECHUNK 64          // edges per wave work-stealing chunk

struct WsHdr {
    float Mt[128];         // Mt[k][h] = (W_edge_att @ W_edge)^T
    float sumh[8];
    int   flags;           // edge_index is int64?
    int   bar1, bar2, work;
};

__device__ __forceinline__ half8 pack8(float4 a, float4 b) {
    half8 r;
    r[0] = (_Float16)a.x; r[1] = (_Float16)a.y; r[2] = (_Float16)a.z; r[3] = (_Float16)a.w;
    r[4] = (_Float16)b.x; r[5] = (_Float16)b.y; r[6] = (_Float16)b.z; r[7] = (_Float16)b.w;
    return r;
}

// ---------------------------------------------------------------- pre: Mt, flags, counters
__global__ __launch_bounds__(256) void pre_kernel(
        const float* __restrict__ W_edge, const float* __restrict__ W_edge_att,
        const int* __restrict__ ei, WsHdr* __restrict__ hdr) {
    int tid = threadIdx.x;
    if (tid < 128) {
        int h = tid >> 4, k = tid & 15;
        float acc = 0.f;
#pragma unroll 8
        for (int j = 0; j < 64; ++j)
            acc += W_edge_att[h * 64 + j] * W_edge[j * 16 + k];
        hdr->Mt[k * 8 + h] = acc;
    }
    if (tid < 8) hdr->sumh[tid] = 0.f;
    if (tid == 0) {
        int zc = 0;        // int64 edge_index: odd int32 words all zero
        for (int i = 1; i < 128; i += 2) zc += (ei[i] == 0);
        hdr->flags = (zc >= 60) ? 1 : 0;
        hdr->bar1 = 0; hdr->bar2 = 0; hdr->work = 0;
    }
}

// Software grid barrier: release-fence + arrive + spin + acquire-fence.
// Safe because GRID_BLKS == 4 blocks/CU x 256 CUs and __launch_bounds__(256,4)
// forces VGPR<=128, LDS<=40KB -> all blocks co-resident.
__device__ __forceinline__ void grid_barrier(int* ctr) {
    __syncthreads();                       // drains each wave's vmem (atomics done)
    if (threadIdx.x == 0) {
        __threadfence();                   // release: writeback this XCD's L2
        atomicAdd(ctr, 1);
        while (atomicAdd(ctr, 0) < GRID_BLKS) __builtin_amdgcn_s_sleep(2);
        __threadfence();                   // acquire: invalidate stale L1/L2
    }
    __syncthreads();
}

// ---------------------------------------------------------------- fused 3-phase kernel
__global__ __launch_bounds__(256, 4) void fused_kernel(
        const float* __restrict__ x, const float* __restrict__ W,
        const float* __restrict__ W_att, const float* __restrict__ edge_attr,
        const int* __restrict__ ei, const float* __restrict__ W_out,
        WsHdr* __restrict__ hdr, __half* __restrict__ g16,
        float* __restrict__ S, float* __restrict__ out, int N, int E) {
    __shared__ union {
        struct { _Float16 sxh[16 * 136]; float h[16 * 68]; } g;   // 8.7 KB
        struct { float sMt[128]; float wsum[4][8]; } e;           // 0.6 KB
        struct { float sWo[8 * 68]; float sAgg[32 * 68]; float sSum[8]; } o; // 10.9 KB
    } sm;
    int tid = threadIdx.x;
    int lane = tid & 63, wave = tid >> 6;

    // ================= Phase 1: g16 = fp16( (x @ W^T) @ W_att^T per head ), S = 0
    {
        int m = lane & 15, quad = lane >> 4;
        // B-frags: wave w owns output cols w*16..w*16+15; B[n=lane&15][k=quad*8+j] = W[n0+n][k]
        half8 bfr[4];
        {
            const float* wrow = W + (size_t)(wave * 16 + m) * 128 + quad * 8;
#pragma unroll
            for (int kc = 0; kc < 4; ++kc)
                bfr[kc] = pack8(*(const float4*)(wrow + kc * 32),
                                *(const float4*)(wrow + kc * 32 + 4));
        }
        int ntiles = (N + GT - 1) / GT;
        for (int t = blockIdx.x; t < ntiles; t += GRID_BLKS) {
            int nbase = t * GT;
            __syncthreads();
            {   // stage 16x128 x-rows as fp16 (coalesced)
                int row = tid >> 4, c8 = (tid & 15) * 8;
                int n = nbase + row;
                float4 f0 = make_float4(0.f, 0.f, 0.f, 0.f), f1 = f0;
                if (n < N) {
                    const float4* xp = (const float4*)(x + (size_t)n * 128 + c8);
                    f0 = xp[0]; f1 = xp[1];
                }
                *(half8*)&sm.g.sxh[row * 136 + c8] = pack8(f0, f1);
            }
            __syncthreads();
            f32x4 acc = {0.f, 0.f, 0.f, 0.f};
#pragma unroll
            for (int kc = 0; kc < 4; ++kc) {  // A[m=lane&15][k=quad*8+j]
                half8 a = *(const half8*)&sm.g.sxh[m * 136 + kc * 32 + quad * 8];
                acc = __builtin_amdgcn_mfma_f32_16x16x32_f16(a, bfr[kc], acc, 0, 0, 0);
            }
            // D: col=lane&15, row=quad*4+reg -> stash h_raw tile in LDS
#pragma unroll
            for (int r = 0; r < 4; ++r)
                sm.g.h[(quad * 4 + r) * 68 + wave * 16 + m] = acc[r];
            __syncthreads();
            if (tid < 128) {                  // W_att 8x8 transform -> g16
                int row = tid >> 3, q = tid & 7;
                int n = nbase + row;
                if (n < N) {
                    float4 h0 = *(const float4*)&sm.g.h[row * 68 + q * 8];
                    float4 h1 = *(const float4*)&sm.g.h[row * 68 + q * 8 + 4];
                    float o8[8];
#pragma unroll
                    for (int k = 0; k < 8; ++k) {
                        float4 w0 = ((const float4*)W_att)[k * 2];
                        float4 w1 = ((const float4*)W_att)[k * 2 + 1];
                        o8[k] = h0.x * w0.x + h0.y * w0.y + h0.z * w0.z + h0.w * w0.w
                              + h1.x * w1.x + h1.y * w1.y + h1.z * w1.z + h1.w * w1.w;
                    }
                    __half2 p0 = __floats2half2_rn(o8[0], o8[1]);
                    __half2 p1 = __floats2half2_rn(o8[2], o8[3]);
                    __half2 p2 = __floats2half2_rn(o8[4], o8[5]);
                    __half2 p3 = __floats2half2_rn(o8[6], o8[7]);
                    uint4 uv = make_uint4(*(unsigned*)&p0, *(unsigned*)&p1,
                                          *(unsigned*)&p2, *(unsigned*)&p3);
                    ((uint4*)g16)[(size_t)n * 8 + q] = uv;
                }
            } else {                          // zero S (ws is poisoned)
                int u = tid - 128;
                int n = nbase + (u >> 3);
                if (n < N) S[(size_t)n * 8 + (u & 7)] = 0.f;
            }
        }
    }
    grid_barrier(&hdr->bar1);

    // ================= Phase 2: edge pass, per-wave work-stealing (64-edge chunks)
    {
        if (tid < 128) sm.e.sMt[tid] = hdr->Mt[tid];
        __syncthreads();
        int idx64 = hdr->flags;
        int h = lane & 7, grp = lane >> 3;     // 8 edge-groups per wave
        const uint4* g16v = (const uint4*)g16;
        float wacc = 0.f;
        int nchunks = (E + ECHUNK - 1) / ECHUNK;
        for (;;) {
            int c;
            if (lane == 0) c = atomicAdd(&hdr->work, 1);
            c = __shfl(c, 0, 64);
            if (c >= nchunks) break;
            int ebase = c * ECHUNK;
            int sIdx[8], dIdx[8];
            if (idx64) {
                const long long* ei64 = (const long long*)ei;
#pragma unroll
                for (int it = 0; it < 8; ++it) {
                    int e = ebase + it * 8 + grp;
                    sIdx[it] = (e < E) ? (int)ei64[e] : 0;
                    dIdx[it] = (e < E) ? (int)ei64[(size_t)E + e] : 0;
                }
            } else {
#pragma unroll
                for (int it = 0; it < 8; ++it) {
                    int e = ebase + it * 8 + grp;
                    sIdx[it] = (e < E) ? ei[e] : 0;
                    dIdx[it] = (e < E) ? ei[(size_t)E + e] : 0;
                }
            }
            uint4 gsv[4], gdv[4];
            float4 at[2][4];
#pragma unroll
            for (int it = 0; it < 3; ++it) {   // prime gathers (depth 4)
                gsv[it] = g16v[(size_t)sIdx[it] * 8 + h];
                gdv[it] = g16v[(size_t)dIdx[it] * 8 + h];
            }
            {
                int e = ebase + grp;
                if (e < E) {
                    const float4* p = (const float4*)(edge_attr + (size_t)e * 16);
                    at[0][0] = p[0]; at[0][1] = p[1]; at[0][2] = p[2]; at[0][3] = p[3];
                }
            }
#pragma unroll
            for (int it = 0; it < 8; ++it) {
                if (it + 3 < 8) {
                    gsv[(it + 3) & 3] = g16v[(size_t)sIdx[it + 3] * 8 + h];
                    gdv[(it + 3) & 3] = g16v[(size_t)dIdx[it + 3] * 8 + h];
                }
                if (it + 1 < 8) {
                    int e2 = ebase + (it + 1) * 8 + grp;
                    if (e2 < E) {
                        const float4* p = (const float4*)(edge_attr + (size_t)e2 * 16);
                        at[(it + 1) & 1][0] = p[0]; at[(it + 1) & 1][1] = p[1];
                        at[(it + 1) & 1][2] = p[2]; at[(it + 1) & 1][3] = p[3];
                    }
                }
                int e = ebase + it * 8 + grp;
                if (e < E) {
                    float4 v0 = at[it & 1][0], v1 = at[it & 1][1],
                           v2 = at[it & 1][2], v3 = at[it & 1][3];
                    const float* sMt = sm.e.sMt;
                    float ea =
                        sMt[0*8+h]*v0.x + sMt[1*8+h]*v0.y + sMt[2*8+h]*v0.z + sMt[3*8+h]*v0.w +
                        sMt[4*8+h]*v1.x + sMt[5*8+h]*v1.y + sMt[6*8+h]*v1.z + sMt[7*8+h]*v1.w +
                        sMt[8*8+h]*v2.x + sMt[9*8+h]*v2.y + sMt[10*8+h]*v2.z + sMt[11*8+h]*v2.w +
                        sMt[12*8+h]*v3.x + sMt[13*8+h]*v3.y + sMt[14*8+h]*v3.z + sMt[15*8+h]*v3.w;
                    const __half2* a2 = (const __half2*)&gsv[it & 3];
                    const __half2* b2 = (const __half2*)&gdv[it & 3];
                    float dot = 0.f;
#pragma unroll
                    for (int j = 0; j < 4; ++j) {
                        float2 fa = __half22float2(a2[j]);
                        float2 fb = __half22float2(b2[j]);
                        dot += fa.x * fb.x + fa.y * fb.y;
                    }
                    float tt = dot + 8.f * ea;             // edge_term = ea * D
                    tt = (tt > 0.f) ? tt : 0.2f * tt;      // leaky_relu(0.2)
                    float w = expf(tt);
                    unsafeAtomicAdd(S + (size_t)dIdx[it] * 8 + h, w);
                    wacc += w;
                }
            }
        }
        wacc += __shfl_xor(wacc, 8, 64);
        wacc += __shfl_xor(wacc, 16, 64);
        wacc += __shfl_xor(wacc, 32, 64);
        if (lane < 8) sm.e.wsum[wave][lane] = wacc;
        __syncthreads();
        if (tid < 8)
            unsafeAtomicAdd(&hdr->sumh[tid],
                sm.e.wsum[0][tid] + sm.e.wsum[1][tid] +
                sm.e.wsum[2][tid] + sm.e.wsum[3][tid]);
    }
    grid_barrier(&hdr->bar2);

    // ================= Phase 3: out = relu(((g16 .* S) / sum_h) @ W_out.T)
    {
        if (tid < 8) sm.o.sSum[tid] = hdr->sumh[tid];
        __syncthreads();
        for (int idx = tid; idx < 512; idx += 256) {
            int k = idx >> 6, j = idx & 63;
            sm.o.sWo[k * 68 + j] = W_out[idx] / sm.o.sSum[j >> 3];  // fold denom
        }
        int ntiles = (N + 31) / 32;
        for (int t = blockIdx.x; t < ntiles; t += GRID_BLKS) {
            int nbase = t * 32;
            __syncthreads();
            {
                int row = tid >> 3, q = tid & 7;
                int n = nbase + row;
                float4 v0 = make_float4(0.f, 0.f, 0.f, 0.f), v1 = v0;
                if (n < N) {
                    uint4 gv = ((const uint4*)g16)[(size_t)n * 8 + q];
                    float sv = S[(size_t)n * 8 + q];
                    const __half2* hp = (const __half2*)&gv;
                    float2 f0 = __half22float2(hp[0]);
                    float2 f1 = __half22float2(hp[1]);
                    float2 f2 = __half22float2(hp[2]);
                    float2 f3 = __half22float2(hp[3]);
                    v0 = make_float4(f0.x * sv, f0.y * sv, f1.x * sv, f1.y * sv);
                    v1 = make_float4(f2.x * sv, f2.y * sv, f3.x * sv, f3.y * sv);
                }
                *(float4*)&sm.o.sAgg[row * 68 + q * 8] = v0;
                *(float4*)&sm.o.sAgg[row * 68 + q * 8 + 4] = v1;
            }
            __syncthreads();
            int nl = tid >> 3, k = tid & 7;
            int n = nbase + nl;
            float acc = 0.f;
#pragma unroll
            for (int j = 0; j < 64; j += 4) {
                float4 av = *(const float4*)&sm.o.sAgg[nl * 68 + j];
                float4 wv = *(const float4*)&sm.o.sWo[k * 68 + j];
                acc += av.x * wv.x + av.y * wv.y + av.z * wv.z + av.w * wv.w;
            }
            if (n < N)
                out[(size_t)n * 8 + k] = (acc > 0.f) ? acc : 0.f;
        }
    }
}

extern "C" void kernel_launch(void* const* d_in, const int* in_sizes, int n_in,
                              void* d_out, int out_size, void* d_ws, size_t ws_size,
                              hipStream_t stream) {
    const float* x          = (const float*)d_in[0];
    const float* edge_attr  = (const float*)d_in[1];
    const float* W          = (const float*)d_in[2];
    const float* W_edge     = (const float*)d_in[3];
    const float* W_edge_att = (const float*)d_in[4];
    const float* W_att      = (const float*)d_in[5];
    const float* W_out      = (const float*)d_in[6];
    const int*   ei         = (const int*)d_in[7];
    float* out = (float*)d_out;

    int N = in_sizes[0] / 128;   // 50000
    int E = in_sizes[1] / 16;    // 800000

    char* wsb = (char*)d_ws;
    WsHdr* hdr = (WsHdr*)wsb;                                  // 1 KB slot
    __half* g16 = (__half*)(wsb + 1024);                       // N*64 fp16
    float*  S   = (float*)(wsb + 1024 + (size_t)N * 64 * 2);   // N*8 fp32
    // total ~8 MB of ws

    hipLaunchKernelGGL(pre_kernel, dim3(1), dim3(256), 0, stream,
                       W_edge, W_edge_att, ei, hdr);
    hipLaunchKernelGGL(fused_kernel, dim3(GRID_BLKS), dim3(256), 0, stream,
                       x, W, W_att, edge_attr, ei, W_out, hdr, g16, S, out, N, E);
}